// Round 10
// baseline (61.704 us; speedup 1.0000x reference)
//
#include <hip/hip_runtime.h>
#include <hip/hip_bf16.h>
#include <math.h>

constexpr int IN_F = 128, OUT_F = 256, NH = 4, HD = 64;
constexpr int B = 8, N = 1024;
#define NEG 0.2f

typedef __attribute__((ext_vector_type(8))) short bf16x8;
typedef __attribute__((ext_vector_type(4))) float f32x4;
typedef __attribute__((ext_vector_type(8))) unsigned short u16x8;

static __device__ __forceinline__ short f2bf(float f) {
    __hip_bfloat16 b = __float2bfloat16(f);
    return *reinterpret_cast<short*>(&b);
}

// ---------------- Kernel 0: bit-pack adjacency -> pkdT [B][16][32 w2][64 rows] ----------------
// grid = 256 blocks, bid%8 = b (XCD-local production). Coalesced reads and writes.
__global__ __launch_bounds__(256) void k_pack(
    const int* __restrict__ adj,          // [B*N, N]
    unsigned* __restrict__ pkdT)
{
    __shared__ unsigned tr[32][33];       // [row][w2], padded
    const int bid = blockIdx.x;
    const int b = bid & 7, ch = bid >> 3; // ch = 32-row chunk 0..31
    const int t = threadIdx.x, lane = t & 63, w = t >> 6;
    const int n0 = ch * 32;

    for (int rr = 0; rr < 8; ++rr) {
        const int rloc = w * 8 + rr;
        const int* __restrict__ src = adj + ((size_t)b * N + n0 + rloc) * N;
        unsigned myw = 0;
#pragma unroll
        for (int c = 0; c < 16; ++c) {
            const unsigned long long m = __ballot(src[c * 64 + lane] != 0);
            const unsigned lo = (unsigned)m, hi = (unsigned)(m >> 32);
            if ((lane >> 1) == c) myw = (lane & 1) ? hi : lo;
        }
        if (lane < 32) tr[rloc][lane] = myw;
    }
    __syncthreads();

    const int w2 = t >> 3, r4 = (t & 7) * 4;
    uint4 v;
    v.x = tr[r4 + 0][w2]; v.y = tr[r4 + 1][w2];
    v.z = tr[r4 + 2][w2]; v.w = tr[r4 + 3][w2];
    unsigned* __restrict__ dst = pkdT + ((size_t)(b * 16 + (ch >> 1))) * 32 * 64
                               + (size_t)w2 * 64 + (ch & 1) * 32 + r4;
    *(uint4*)dst = v;
}

// ---------------- Kernel 1: h = x @ W (round-2 proven version), b-swizzled grid ----------------
__global__ __launch_bounds__(256) void k_gemm(
    const float* __restrict__ x,          // [B*N, 128]
    const float* __restrict__ W,          // [128, 256]
    const float* __restrict__ a,          // [128]
    unsigned short* __restrict__ hT,      // [B][H][64][N] bf16 bits (transposed)
    float* __restrict__ siT,              // [B][H][N]
    float* __restrict__ sjT)              // [B][H][N]
{
    constexpr int ROWS = 8;
    __shared__ float xs[ROWS][IN_F];   // 4 KB
    const int t = threadIdx.x;
    const int bid = blockIdx.x;
    const int b = bid & 7, rg = bid >> 3;          // XCD-local: hT[b] stays on XCD b
    const int row0 = b * N + rg * ROWS;

    ((float4*)xs)[t] = ((const float4*)(x + (size_t)row0 * IN_F))[t];
    __syncthreads();

    float acc[ROWS];
#pragma unroll
    for (int r = 0; r < ROWS; ++r) acc[r] = 0.f;
    for (int k = 0; k < IN_F; ++k) {
        const float w = W[k * OUT_F + t];   // coalesced across t
#pragma unroll
        for (int r = 0; r < ROWS; ++r) acc[r] = fmaf(xs[r][k], w, acc[r]);
    }

    const int lane = t & 63, head = t >> 6, d = t & 63;
    const int n0 = rg * ROWS;

    u16x8 pk;
#pragma unroll
    for (int r = 0; r < ROWS; ++r) pk[r] = (unsigned short)f2bf(acc[r]);
    *(u16x8*)&hT[((size_t)(b * NH + head) * HD + d) * N + n0] = pk;

    const float ai = a[lane], aj = a[HD + lane];
#pragma unroll
    for (int r = 0; r < ROWS; ++r) {
        float si = acc[r] * ai;
        float sj = acc[r] * aj;
#pragma unroll
        for (int off = 32; off; off >>= 1) {
            si += __shfl_xor(si, off, 64);
            sj += __shfl_xor(sj, off, 64);
        }
        if (lane == 0) {
            siT[(size_t)(b * NH + head) * N + n0 + r] = si;
            sjT[(size_t)(b * NH + head) * N + n0 + r] = sj;
        }
    }
}

// ---------------- Kernel 2: MFMA PV; j-half split (grid 1024, 16 waves/CU), atomic combine ----------------
// bid%8 = b (XCD-local hT reads). Block = (b, h, itile64, jh): 4 waves x 16 i-rows, 512 j's.
__global__ __launch_bounds__(256, 4) void k_pv(
    const unsigned short* __restrict__ hT,   // [B][H][64][N] bf16
    const float* __restrict__ siT,           // [B][H][N]
    const float* __restrict__ sjT,           // [B][H][N]
    const unsigned* __restrict__ pkdT,       // [B][16][32][64] packed bits
    float* __restrict__ out,                 // [B][N][256]  (accumulated, unnormalized)
    float* __restrict__ Z)                   // [B][H][N]    (accumulated)
{
    constexpr int TJ = 64, NIT = 8, PADJ = 72;
    __shared__ __align__(16) short ht[2][64 * PADJ];  // 18 KB h-tile [d][j]
    __shared__ float sjs[N];                          // 4 KB (full row; reads use global j)
    __shared__ unsigned pwl[16 * 64];                 // 4 KB [w2 local][row]

    const int bid = blockIdx.x;
    const int b = bid & 7, r = bid >> 3;
    const int h = r & 3, itile = (r >> 2) & 15, jh = (r >> 6) & 1;
    const int t = threadIdx.x, lane = t & 63, w = t >> 6;
    const int i0 = itile * 64;
    const int jbase = jh << 9;

    ((float4*)sjs)[t] = ((const float4*)(sjT + (size_t)(b * NH + h) * N))[t];
    {   // stage this j-half's packed bits: 4 KB
        const uint4* ps = (const uint4*)(pkdT + ((size_t)(b * 16 + itile)) * 32 * 64
                                         + (size_t)jh * 16 * 64);
        ((uint4*)pwl)[t] = ps[t];
    }

    const int il = lane & 15, q = lane >> 4, qc = q * 8;
    const int lr = w * 16 + il;              // local i-row (wave w owns rows i0+16w..+16)
    const float si = siT[(size_t)(b * NH + h) * N + i0 + lr];

    // staging: thread t owns h-row t>>2, col chunk (t&3)*16 within the 64-col tile
    const int srow = t >> 2, sc = (t & 3) * 16;
    const unsigned short* __restrict__ hsrc =
        hT + (size_t)(b * NH + h) * HD * N + (size_t)srow * N + sc + jbase;
    short* const hd0 = &ht[0][srow * PADJ + sc];
    short* const hd1 = &ht[1][srow * PADJ + sc];

    f32x4 acc0 = {0.f,0.f,0.f,0.f}, acc1 = {0.f,0.f,0.f,0.f};
    f32x4 acc2 = {0.f,0.f,0.f,0.f}, acc3 = {0.f,0.f,0.f,0.f};
    float psA = 0.f, psB = 0.f;

    u16x8 ra = *(const u16x8*)(hsrc);
    u16x8 rc = *(const u16x8*)(hsrc + 8);

    for (int itr = 0; itr < NIT; ++itr) {
        short* const hd = (itr & 1) ? hd1 : hd0;
        *(u16x8*)hd = ra;
        *(u16x8*)(hd + 8) = rc;

        const int jn = ((itr + 1) & (NIT - 1)) * TJ;   // wrap within half
        ra = *(const u16x8*)(hsrc + jn);
        rc = *(const u16x8*)(hsrc + jn + 8);

        __syncthreads();
        const short* const hb = (itr & 1) ? ht[1] : ht[0];
        const int j0 = jbase + itr * TJ;

#define STEP(ks, PS)                                                         \
        {                                                                    \
            const unsigned byte = (pwl[(2 * itr + (ks)) * 64 + lr] >> qc) & 0xffu; \
            const int jq = j0 + (ks) * 32 + qc;                              \
            const float4 s0 = *(const float4*)&sjs[jq];                      \
            const float4 s1 = *(const float4*)&sjs[jq + 4];                  \
            const float sv[8] = {s0.x,s0.y,s0.z,s0.w,s1.x,s1.y,s1.z,s1.w};   \
            bf16x8 af;                                                       \
            _Pragma("unroll")                                                \
            for (int e = 0; e < 8; ++e) {                                    \
                const float ev0 = si + sv[e];                                \
                const float ev = fmaxf(ev0, NEG * ev0);                      \
                const float pe = ((byte >> e) & 1u) ? __expf(ev) : 0.f;      \
                PS += pe;                                                    \
                af[e] = f2bf(pe);                                            \
            }                                                                \
            const bf16x8 b0 = *(const bf16x8*)&hb[(0*16 + il)*PADJ + (ks)*32 + qc]; \
            const bf16x8 b1 = *(const bf16x8*)&hb[(1*16 + il)*PADJ + (ks)*32 + qc]; \
            const bf16x8 b2 = *(const bf16x8*)&hb[(2*16 + il)*PADJ + (ks)*32 + qc]; \
            const bf16x8 b3 = *(const bf16x8*)&hb[(3*16 + il)*PADJ + (ks)*32 + qc]; \
            acc0 = __builtin_amdgcn_mfma_f32_16x16x32_bf16(af, b0, acc0, 0, 0, 0); \
            acc1 = __builtin_amdgcn_mfma_f32_16x16x32_bf16(af, b1, acc1, 0, 0, 0); \
            acc2 = __builtin_amdgcn_mfma_f32_16x16x32_bf16(af, b2, acc2, 0, 0, 0); \
            acc3 = __builtin_amdgcn_mfma_f32_16x16x32_bf16(af, b3, acc3, 0, 0, 0); \
        }
        STEP(0, psA)
        STEP(1, psB)
#undef STEP
        __syncthreads();
    }

    // ---- Z partial: reduce over the 4 k-quarter lane groups, atomic-accumulate
    float ps = psA + psB;
    ps += __shfl_xor(ps, 16, 64);
    ps += __shfl_xor(ps, 32, 64);
    if (lane < 16)
        atomicAdd(&Z[(size_t)(b * NH + h) * N + i0 + w * 16 + lane], ps);

    // ---- epilogue: atomic-accumulate unnormalized acc (C/D: col=lane&15, row=q*4+reg)
    float* __restrict__ ob = out + ((size_t)b * N + i0 + w * 16) * OUT_F + h * HD + il;
#pragma unroll
    for (int rr = 0; rr < 4; ++rr) {
        float* o = ob + (size_t)(q * 4 + rr) * OUT_F;
        atomicAdd(&o[0],  acc0[rr]);
        atomicAdd(&o[16], acc1[rr]);
        atomicAdd(&o[32], acc2[rr]);
        atomicAdd(&o[48], acc3[rr]);
    }
}

// ---------------- Kernel 3: normalize out by Z ----------------
// grid = 2048 blocks x 256 threads, float4 each.
__global__ __launch_bounds__(256) void k_norm(
    float* __restrict__ out,              // [B*N, 256]
    const float* __restrict__ Z)          // [B][H][N]
{
    const int idx = blockIdx.x * 256 + threadIdx.x;
    const int fi = idx * 4;
    const int ng = fi >> 8;               // global row 0..8191
    const int c = fi & 255, h = c >> 6;
    const int b = ng >> 10, n = ng & (N - 1);
    const float z = Z[((size_t)(b * NH + h)) * N + n];
    const float s = 1.f / z;
    float4 v = ((float4*)out)[idx];
    v.x *= s; v.y *= s; v.z *= s; v.w *= s;
    ((float4*)out)[idx] = v;
}

extern "C" void kernel_launch(void* const* d_in, const int* in_sizes, int n_in,
                              void* d_out, int out_size, void* d_ws, size_t ws_size,
                              hipStream_t stream) {
    const float* x   = (const float*)d_in[0];
    const int*   adj = (const int*)d_in[1];
    const float* W   = (const float*)d_in[2];
    const float* a   = (const float*)d_in[3];
    float* out = (float*)d_out;

    unsigned short* hT = (unsigned short*)d_ws;                        // 4 MB bf16
    float* siT = (float*)(hT + (size_t)B * NH * HD * N);               // 128 KB
    float* sjT = siT + (size_t)B * NH * N;                             // 128 KB
    unsigned* pkdT = (unsigned*)(sjT + (size_t)B * NH * N);            // 1 MB
    float* Z = (float*)(pkdT + (size_t)B * 16 * 32 * 64);              // 128 KB

    hipMemsetAsync(out, 0, (size_t)out_size * sizeof(float), stream);
    hipMemsetAsync(Z, 0, (size_t)B * NH * N * sizeof(float), stream);

    k_pack<<<B * 32, 256, 0, stream>>>(adj, pkdT);
    k_gemm<<<B * N / 8, 256, 0, stream>>>(x, W, a, hT, siT, sjT);
    k_pv<<<B * NH * (N / 64) * 2, 256, 0, stream>>>(hT, siT, sjT, pkdT, out, Z);
    k_norm<<<(B * N * OUT_F / 4) / 256, 256, 0, stream>>>(out, Z);
}

// Round 11
// 52.203 us; speedup vs baseline: 1.1820x; 1.1820x over previous
//
#include <hip/hip_runtime.h>
#include <hip/hip_bf16.h>
#include <math.h>

constexpr int IN_F = 128, OUT_F = 256, NH = 4, HD = 64;
constexpr int B = 8, N = 1024;
#define NEG 0.2f

typedef __attribute__((ext_vector_type(8))) short bf16x8;
typedef __attribute__((ext_vector_type(4))) float f32x4;
typedef __attribute__((ext_vector_type(8))) unsigned short u16x8;

static __device__ __forceinline__ short f2bf(float f) {
    __hip_bfloat16 b = __float2bfloat16(f);
    return *reinterpret_cast<short*>(&b);
}

// ---------------- Kernel 0: bit-pack adjacency -> pkdT [B][16][32 w2][64 rows] ----------------
// grid = B*128 = 1024 blocks (8 rows each), 256 threads. 4 blocks/CU -> HBM-stream with TLP.
__global__ __launch_bounds__(256) void k_pack(
    const int* __restrict__ adj,          // [B*N, N]
    unsigned* __restrict__ pkdT)
{
    __shared__ unsigned tr[8][33];        // [row][w2], padded
    const int bid = blockIdx.x;
    const int b = bid & 7, ch = bid >> 3; // ch = 8-row chunk 0..127
    const int t = threadIdx.x, lane = t & 63, w = t >> 6;
    const int n0 = ch * 8;

#pragma unroll
    for (int rr = 0; rr < 2; ++rr) {
        const int rloc = w * 2 + rr;
        const int* __restrict__ src = adj + ((size_t)b * N + n0 + rloc) * N;
        unsigned myw = 0;
#pragma unroll
        for (int c = 0; c < 16; ++c) {
            const unsigned long long m = __ballot(src[c * 64 + lane] != 0);
            const unsigned lo = (unsigned)m, hi = (unsigned)(m >> 32);
            if ((lane >> 1) == c) myw = (lane & 1) ? hi : lo;
        }
        if (lane < 32) tr[rloc][lane] = myw;
    }
    __syncthreads();

    // 256 words out: thread t -> w2 = t>>3, row r = t&7 (8-word segments, coalesced-ish)
    const int w2 = t >> 3, r = t & 7;
    unsigned* __restrict__ dst = pkdT + ((size_t)(b * 16 + (n0 >> 6))) * 32 * 64
                               + (size_t)w2 * 64 + (n0 & 63) + r;
    *dst = tr[r][w2];
}

// ---------------- Kernel 1: h = x @ W (round-2 proven version), b-swizzled grid ----------------
__global__ __launch_bounds__(256) void k_gemm(
    const float* __restrict__ x,          // [B*N, 128]
    const float* __restrict__ W,          // [128, 256]
    const float* __restrict__ a,          // [128]
    unsigned short* __restrict__ hT,      // [B][H][64][N] bf16 bits (transposed)
    float* __restrict__ siT,              // [B][H][N]
    float* __restrict__ sjT)              // [B][H][N]
{
    constexpr int ROWS = 8;
    __shared__ float xs[ROWS][IN_F];   // 4 KB
    const int t = threadIdx.x;
    const int bid = blockIdx.x;
    const int b = bid & 7, rg = bid >> 3;          // XCD-local: hT[b] stays on XCD b
    const int row0 = b * N + rg * ROWS;

    ((float4*)xs)[t] = ((const float4*)(x + (size_t)row0 * IN_F))[t];
    __syncthreads();

    float acc[ROWS];
#pragma unroll
    for (int r = 0; r < ROWS; ++r) acc[r] = 0.f;
    for (int k = 0; k < IN_F; ++k) {
        const float w = W[k * OUT_F + t];   // coalesced across t; xs read is broadcast
#pragma unroll
        for (int r = 0; r < ROWS; ++r) acc[r] = fmaf(xs[r][k], w, acc[r]);
    }

    const int lane = t & 63, head = t >> 6, d = t & 63;
    const int n0 = rg * ROWS;

    u16x8 pk;
#pragma unroll
    for (int r = 0; r < ROWS; ++r) pk[r] = (unsigned short)f2bf(acc[r]);
    *(u16x8*)&hT[((size_t)(b * NH + head) * HD + d) * N + n0] = pk;

    const float ai = a[lane], aj = a[HD + lane];
#pragma unroll
    for (int r = 0; r < ROWS; ++r) {
        float si = acc[r] * ai;
        float sj = acc[r] * aj;
#pragma unroll
        for (int off = 32; off; off >>= 1) {
            si += __shfl_xor(si, off, 64);
            sj += __shfl_xor(sj, off, 64);
        }
        if (lane == 0) {
            siT[(size_t)(b * NH + head) * N + n0 + r] = si;
            sjT[(size_t)(b * NH + head) * N + n0 + r] = sj;
        }
    }
}

// ---------------- Kernel 2: MFMA PV; d-half split (grid 1024, disjoint outputs, no combine) ----------------
// Block = (b, h, itile64, dh): 4 waves x 16 i-rows x 32 d-dims, all 1024 j.
// Bits in registers (32 u32/lane), one barrier/iter, 13.6 KB LDS, 4 blocks/CU co-resident.
__global__ __launch_bounds__(256, 4) void k_pv(
    const unsigned short* __restrict__ hT,   // [B][H][64][N] bf16
    const float* __restrict__ siT,           // [B][H][N]
    const float* __restrict__ sjT,           // [B][H][N]
    const unsigned* __restrict__ pkdT,       // [B][16][32][64] packed bits
    float* __restrict__ out)                 // [B][N][256]
{
    constexpr int TJ = 64, NIT = N / TJ, PADJ = 72;
    __shared__ __align__(16) short ht[2][32 * PADJ];  // 9 KB h-tile [d_local][j]
    __shared__ float sjs[N];                          // 4 KB
    __shared__ float zbuf[4][16];

    const int bid = blockIdx.x;
    const int b = bid & 7, r = bid >> 3;
    const int h = r & 3, itile = (r >> 2) & 15, dh = (r >> 6) & 1;
    const int t = threadIdx.x, lane = t & 63, w = t >> 6;
    const int i0 = itile * 64;

    ((float4*)sjs)[t] = ((const float4*)(sjT + (size_t)(b * NH + h) * N))[t];

    const int il = lane & 15, q = lane >> 4, qc = q * 8;
    const int lr = w * 16 + il;              // local i-row
    const float si = siT[(size_t)(b * NH + h) * N + i0 + lr];

    // ---- adjacency bits for this lane's i-row: 32 words -> registers (coalesced 4B loads)
    unsigned bw[32];
    {
        const unsigned* __restrict__ pb = pkdT + ((size_t)(b * 16 + itile)) * 32 * 64 + lr;
#pragma unroll
        for (int k = 0; k < 32; ++k) bw[k] = pb[(size_t)k * 64];
    }

    // staging: thread t owns tile row t>>3 (d_local 0..31), col chunk (t&7)*8 (16 B)
    const int srow = t >> 3, sc = (t & 7) * 8;
    const unsigned short* __restrict__ hsrc =
        hT + (size_t)(b * NH + h) * HD * N + (size_t)(dh * 32 + srow) * N + sc;
    short* const hd0 = &ht[0][srow * PADJ + sc];
    short* const hd1 = &ht[1][srow * PADJ + sc];

    f32x4 acc0 = {0.f,0.f,0.f,0.f}, acc1 = {0.f,0.f,0.f,0.f};
    float psA = 0.f, psB = 0.f;

    u16x8 ra = *(const u16x8*)(hsrc);        // preload tile 0

#pragma unroll
    for (int itr = 0; itr < NIT; ++itr) {
        // write current tile (dbuf parity itr&1), then prefetch next
        short* const hd = (itr & 1) ? hd1 : hd0;
        *(u16x8*)hd = ra;
        const int jn = ((itr + 1) & (NIT - 1)) * TJ;
        ra = *(const u16x8*)(hsrc + jn);

        __syncthreads();                     // single barrier per iter (write->read race-free)
        const short* const hb = (itr & 1) ? ht[1] : ht[0];

#define STEP(ks, PS)                                                         \
        {                                                                    \
            const unsigned byte = (bw[2 * itr + (ks)] >> qc) & 0xffu;        \
            const int jq = itr * TJ + (ks) * 32 + qc;                        \
            const float4 s0 = *(const float4*)&sjs[jq];                      \
            const float4 s1 = *(const float4*)&sjs[jq + 4];                  \
            const float sv[8] = {s0.x,s0.y,s0.z,s0.w,s1.x,s1.y,s1.z,s1.w};   \
            bf16x8 af;                                                       \
            _Pragma("unroll")                                                \
            for (int e = 0; e < 8; ++e) {                                    \
                const float ev0 = si + sv[e];                                \
                const float ev = fmaxf(ev0, NEG * ev0);                      \
                const float pe = ((byte >> e) & 1u) ? __expf(ev) : 0.f;      \
                PS += pe;                                                    \
                af[e] = f2bf(pe);                                            \
            }                                                                \
            const bf16x8 b0 = *(const bf16x8*)&hb[(il) * PADJ + (ks)*32 + qc];      \
            const bf16x8 b1 = *(const bf16x8*)&hb[(16 + il) * PADJ + (ks)*32 + qc]; \
            acc0 = __builtin_amdgcn_mfma_f32_16x16x32_bf16(af, b0, acc0, 0, 0, 0); \
            acc1 = __builtin_amdgcn_mfma_f32_16x16x32_bf16(af, b1, acc1, 0, 0, 0); \
        }
        STEP(0, psA)
        STEP(1, psB)
#undef STEP
    }

    // ---- Z: reduce psum over the 4 k-quarter lane groups (identical in both dh blocks)
    float ps = psA + psB;
    ps += __shfl_xor(ps, 16, 64);
    ps += __shfl_xor(ps, 32, 64);
    __syncthreads();                          // last iter's reads done before zbuf write? (zbuf separate; barrier orders zbuf r/w)
    if (lane < 16) zbuf[w][lane] = ps;
    __syncthreads();

    // ---- epilogue: C/D layout col = lane&15 (d_local), row = q*4 + reg (i-row)
    float iz[4];
#pragma unroll
    for (int rr = 0; rr < 4; ++rr) iz[rr] = 1.f / zbuf[w][q * 4 + rr];

    float* __restrict__ ob = out + ((size_t)b * N + i0 + w * 16) * OUT_F
                           + h * HD + dh * 32 + il;
#pragma unroll
    for (int rr = 0; rr < 4; ++rr) {
        float* o = ob + (size_t)(q * 4 + rr) * OUT_F;
        o[0]  = acc0[rr] * iz[rr];
        o[16] = acc1[rr] * iz[rr];
    }
}

extern "C" void kernel_launch(void* const* d_in, const int* in_sizes, int n_in,
                              void* d_out, int out_size, void* d_ws, size_t ws_size,
                              hipStream_t stream) {
    const float* x   = (const float*)d_in[0];
    const int*   adj = (const int*)d_in[1];
    const float* W   = (const float*)d_in[2];
    const float* a   = (const float*)d_in[3];
    float* out = (float*)d_out;

    unsigned short* hT = (unsigned short*)d_ws;                        // 4 MB bf16
    float* siT = (float*)(hT + (size_t)B * NH * HD * N);               // 128 KB
    float* sjT = siT + (size_t)B * NH * N;                             // 128 KB
    unsigned* pkdT = (unsigned*)(sjT + (size_t)B * NH * N);            // 1 MB

    k_pack<<<B * 128, 256, 0, stream>>>(adj, pkdT);
    k_gemm<<<B * N / 8, 256, 0, stream>>>(x, W, a, hT, siT, sjT);
    k_pv<<<B * NH * 16 * 2, 256, 0, stream>>>(hT, siT, sjT, pkdT, out);
}